// Round 7
// baseline (1279.998 us; speedup 1.0000x reference)
//
#include <hip/hip_runtime.h>

typedef __attribute__((ext_vector_type(8))) short bf16x8;
typedef __attribute__((ext_vector_type(4))) float f32x4;
typedef __attribute__((ext_vector_type(16))) float f32x16;

__device__ __forceinline__ ushort f2bf(float x) {
  union { float f; unsigned u; } c; c.f = x;
  unsigned u = c.u;
  u += 0x7fffu + ((u >> 16) & 1u);
  return (ushort)(u >> 16);
}

__device__ __forceinline__ unsigned cvt_pk_bf16(float lo, float hi) {
  unsigned r;
  asm("v_cvt_pk_bf16_f32 %0, %1, %2" : "=v"(r) : "v"(lo), "v"(hi));
  return r;
}

// ---------------------------------------------------------------------------
// Transpose A,B [4][4096][128] f32 -> At,Bt [4][128][4096] bf16 (V^T operands)
// ---------------------------------------------------------------------------
__global__ __launch_bounds__(256) void prep_transpose(
    const float* __restrict__ A, const float* __restrict__ Bm,
    ushort* __restrict__ At, ushort* __restrict__ Bt)
{
  int tensor = blockIdx.z & 1, b = blockIdx.z >> 1;
  const float* in = tensor ? Bm : A;
  ushort* out = tensor ? Bt : At;
  int m0 = blockIdx.x * 64, d0 = blockIdx.y * 64;
  __shared__ ushort tile[64][72];
  int tid = threadIdx.x;
#pragma unroll
  for (int it = 0; it < 4; ++it) {
    int lin = it * 256 + tid;
    int r = lin >> 4, c4 = (lin & 15) * 4;
    const float* p = in + ((size_t)b * 4096 + m0 + r) * 128 + d0 + c4;
    float4 v = *(const float4*)p;
    tile[r][c4 + 0] = f2bf(v.x); tile[r][c4 + 1] = f2bf(v.y);
    tile[r][c4 + 2] = f2bf(v.z); tile[r][c4 + 3] = f2bf(v.w);
  }
  __syncthreads();
#pragma unroll
  for (int it = 0; it < 2; ++it) {
    int lin = it * 256 + tid;
    int dr = lin >> 3, cm = (lin & 7) * 8;
    bf16x8 v;
#pragma unroll
    for (int j = 0; j < 8; ++j) v[j] = (short)tile[cm + j][dr];
    *(bf16x8*)(out + ((size_t)b * 128 + d0 + dr) * 4096 + m0 + cm) = v;
  }
}

// ---------------------------------------------------------------------------
// W1[128][256] -> Wt1[256][128] bf16 ; W2[256][256] -> Wt2[256][256] bf16
// ---------------------------------------------------------------------------
__global__ __launch_bounds__(256) void prep_w(
    const float* __restrict__ W1, const float* __restrict__ W2,
    ushort* __restrict__ Wt1, ushort* __restrict__ Wt2)
{
  int idx = blockIdx.x * 256 + threadIdx.x;   // 0..65535
  if (idx < 32768) {
    int k = idx >> 8, n = idx & 255;
    Wt1[n * 128 + k] = f2bf(W1[idx]);
  }
  {
    int k = idx >> 8, n = idx & 255;
    Wt2[n * 256 + k] = f2bf(W2[idx]);
  }
}

// ---------------------------------------------------------------------------
// out = relu(X @ W + bias) bf16, N=256. Wt bf16 [256][KD] from global (L2).
// ---------------------------------------------------------------------------
template<int KD, bool F32IN>
__global__ __launch_bounds__(256) void mlp2(
    const void* __restrict__ X0, const void* __restrict__ X1,
    const ushort* __restrict__ Wt, const float* __restrict__ bias,
    ushort* __restrict__ out0, ushort* __restrict__ out1)
{
  const void* X = blockIdx.y ? X1 : X0;
  ushort* out = blockIdx.y ? out1 : out0;
  int l = threadIdx.x & 63, w = threadIdx.x >> 6;
  int rowbase = blockIdx.x * 64 + w * 16;
  constexpr int NK = KD / 32;
  bf16x8 xf[NK];
  {
    int r = rowbase + (l & 15);
    int koff = (l >> 4) * 8;
    if (F32IN) {
      const float* Xp = (const float*)X + (size_t)r * KD + koff;
#pragma unroll
      for (int kc = 0; kc < NK; ++kc) {
        float4 a = *(const float4*)(Xp + kc * 32);
        float4 c = *(const float4*)(Xp + kc * 32 + 4);
        bf16x8 v;
        v[0] = (short)f2bf(a.x); v[1] = (short)f2bf(a.y);
        v[2] = (short)f2bf(a.z); v[3] = (short)f2bf(a.w);
        v[4] = (short)f2bf(c.x); v[5] = (short)f2bf(c.y);
        v[6] = (short)f2bf(c.z); v[7] = (short)f2bf(c.w);
        xf[kc] = v;
      }
    } else {
      const ushort* Xp = (const ushort*)X + (size_t)r * KD + koff;
#pragma unroll
      for (int kc = 0; kc < NK; ++kc) xf[kc] = *(const bf16x8*)(Xp + kc * 32);
    }
  }
  f32x4 acc[16];
#pragma unroll
  for (int i = 0; i < 16; ++i) acc[i] = (f32x4){0.f, 0.f, 0.f, 0.f};
#pragma unroll
  for (int kc = 0; kc < NK; ++kc) {
#pragma unroll
    for (int nf = 0; nf < 16; ++nf) {
      bf16x8 bfv = *(const bf16x8*)&Wt[(size_t)(nf * 16 + (l & 15)) * KD + kc * 32 + (l >> 4) * 8];
      acc[nf] = __builtin_amdgcn_mfma_f32_16x16x32_bf16(xf[kc], bfv, acc[nf], 0, 0, 0);
    }
  }
#pragma unroll
  for (int nf = 0; nf < 16; ++nf) {
    int col = nf * 16 + (l & 15);
    float bv = bias[col];
#pragma unroll
    for (int i = 0; i < 4; ++i) {
      float v = acc[nf][i] + bv;
      v = fmaxf(v, 0.f);
      out[(size_t)(rowbase + (l >> 4) * 4 + i) * 256 + col] = f2bf(v);
    }
  }
}

// ---------------------------------------------------------------------------
// Flash pass, all-operands-from-L2 + per-tile lockstep barrier (r5 fixed).
// Block = 4 waves on the SAME 32 q-rows; at step t wave w processes keys
// [(4t+w)*32, +32) — interleaved chunks keep the whole XCD in one contiguous
// 128-key window per step. Raw s_barrier each step keeps waves (and
// statistically all co-resident blocks) in lockstep so the per-XCD L2
// working set stays ~few-hundred KB (r5 lesson: without this, 2.7 GB FETCH).
// No LDS in the loop. Grid (8,128) = 1024 blocks -> ~4 blocks/CU.
// End: 2-round pairwise LSE merge via LDS, wave 0 writes output.
// ---------------------------------------------------------------------------
__global__ __launch_bounds__(256, 4) void flash6(
    const ushort* __restrict__ fA, const ushort* __restrict__ fB,
    const ushort* __restrict__ At, const ushort* __restrict__ Bt,
    float* __restrict__ out)
{
  int bp = blockIdx.x;             // 0..7 = pass*4 + b  (XCD-major)
  int pass = bp >> 2, b = bp & 3;
  int qblk = blockIdx.y;           // 0..127
  const ushort* fQ = pass ? fB : fA;
  const ushort* fK = pass ? fA : fB;
  const ushort* Vg = pass ? At : Bt;
  float* O = out + ((size_t)pass * 4 + b) * (4096 * 128);

  __shared__ float shm_acc[2][64][64];   // [slot][lane][j], j swizzled (+l)
  __shared__ float shm_m[2][64];
  __shared__ float shm_l[2][64];

  int tid = threadIdx.x;
  int l = tid & 63, w = tid >> 6;        // w = key-interleave slot 0..3
  int l31 = l & 31, g5 = l >> 5;

  const size_t fbase = (size_t)b * 4096 * 256;
  const size_t vbase = (size_t)b * 128 * 4096;

  // Q regs: B-frag (col = l31 -> qrow, h = st*16 + g5*8 + j)
  bf16x8 q[16];
  {
    const ushort* qp = fQ + fbase + (size_t)(qblk * 32 + l31) * 256 + g5 * 8;
#pragma unroll
    for (int st = 0; st < 16; ++st) q[st] = *(const bf16x8*)(qp + st * 16);
  }

  f32x16 acc0 = {}, acc1 = {}, acc2 = {}, acc3 = {};
  float m_run = -INFINITY, l_run = 0.f;

#pragma unroll 1
  for (int t = 0; t < 32; ++t) {
    __builtin_amdgcn_s_barrier();        // lockstep only; nothing shared

    const int kb0 = (t * 4 + w) * 32;    // this wave's 32-key stripe

    // K fragments from L2: lane l31 = key row, g5*8 = h sub-block
    const ushort* kp = fK + fbase + (size_t)(kb0 + l31) * 256 + g5 * 8;
    bf16x8 ka[16];
#pragma unroll
    for (int st = 0; st < 16; ++st) ka[st] = *(const bf16x8*)(kp + st * 16);

    // V^T fragments: col = l31 -> d-local, k = key-local = kblk*16 + g5*8 + j
    bf16x8 vv[2][4];
#pragma unroll
    for (int db = 0; db < 4; ++db) {
      const ushort* vp = Vg + vbase + (size_t)(db * 32 + l31) * 4096 + kb0 + g5 * 8;
      vv[0][db] = *(const bf16x8*)(vp);
      vv[1][db] = *(const bf16x8*)(vp + 16);
    }

    // QK^T swapped: S^T[key][qrow] = mfma(A=K, B=Q); 2 indep chains.
    __builtin_amdgcn_s_setprio(1);
    f32x16 s0 = {}, s1 = {};
#pragma unroll
    for (int st2 = 0; st2 < 8; ++st2) {
      s0 = __builtin_amdgcn_mfma_f32_32x32x16_bf16(ka[2 * st2],     q[2 * st2],     s0, 0, 0, 0);
      s1 = __builtin_amdgcn_mfma_f32_32x32x16_bf16(ka[2 * st2 + 1], q[2 * st2 + 1], s1, 0, 0, 0);
    }
    __builtin_amdgcn_s_setprio(0);

    // lane: qrow = l31; key-local(r,g5) = (r&3) + 8*(r>>2) + 4*g5
    float sv[16];
#pragma unroll
    for (int r = 0; r < 16; ++r) sv[r] = s0[r] + s1[r];

    // tree max (dep depth 4)
    float mx[16];
#pragma unroll
    for (int r = 0; r < 16; ++r) mx[r] = sv[r];
#pragma unroll
    for (int off = 8; off >= 1; off >>= 1)
#pragma unroll
      for (int r = 0; r < off; ++r) mx[r] = fmaxf(mx[r], mx[r + off]);
    float pmax = fmaxf(mx[0], __shfl_xor(mx[0], 32));

    if (!__all(pmax <= m_run + 8.f)) {       // rare: t=0 / overflow risk only
      float mnew = fmaxf(m_run, pmax);
      float sc = __expf(m_run - mnew);
      l_run *= sc;
#pragma unroll
      for (int r = 0; r < 16; ++r) {
        float scr = __shfl(sc, (r & 3) + 8 * (r >> 2) + 4 * g5);
        acc0[r] *= scr; acc1[r] *= scr; acc2[r] *= scr; acc3[r] *= scr;
      }
      m_run = mnew;
    }

    float p[16];
#pragma unroll
    for (int r = 0; r < 16; ++r) p[r] = __expf(sv[r] - m_run);
    float ps[16];
#pragma unroll
    for (int r = 0; r < 16; ++r) ps[r] = p[r];
#pragma unroll
    for (int off = 8; off >= 1; off >>= 1)
#pragma unroll
      for (int r = 0; r < off; ++r) ps[r] += ps[r + off];
    l_run += ps[0] + __shfl_xor(ps[0], 32);

    // pack P pairs: pk[r2][h] covers key-locals 4*(2*r2 + g5) + {0..3}
    unsigned pk[4][2];
#pragma unroll
    for (int r2 = 0; r2 < 4; ++r2) {
      pk[r2][0] = cvt_pk_bf16(p[4 * r2 + 0], p[4 * r2 + 1]);
      pk[r2][1] = cvt_pk_bf16(p[4 * r2 + 2], p[4 * r2 + 3]);
    }

    // exchange halves -> PV A-frags; PV MFMAs
#pragma unroll
    for (int kblk = 0; kblk < 2; ++kblk) {
      int r2a = 2 * kblk, r2b = r2a + 1;
      unsigned la0 = pk[r2a][0], la1 = pk[r2a][1];
      unsigned lb0 = pk[r2b][0], lb1 = pk[r2b][1];
      unsigned s0w = g5 ? la0 : lb0, s1w = g5 ? la1 : lb1;
      unsigned rc0 = (unsigned)__shfl_xor((int)s0w, 32);
      unsigned rc1 = (unsigned)__shfl_xor((int)s1w, 32);
      union { unsigned u[4]; bf16x8 v; } pf;
      pf.u[0] = g5 ? rc0 : la0;  pf.u[1] = g5 ? rc1 : la1;
      pf.u[2] = g5 ? lb0 : rc0;  pf.u[3] = g5 ? lb1 : rc1;
      __builtin_amdgcn_s_setprio(1);
      acc0 = __builtin_amdgcn_mfma_f32_32x32x16_bf16(pf.v, vv[kblk][0], acc0, 0, 0, 0);
      acc1 = __builtin_amdgcn_mfma_f32_32x32x16_bf16(pf.v, vv[kblk][1], acc1, 0, 0, 0);
      acc2 = __builtin_amdgcn_mfma_f32_32x32x16_bf16(pf.v, vv[kblk][2], acc2, 0, 0, 0);
      acc3 = __builtin_amdgcn_mfma_f32_32x32x16_bf16(pf.v, vv[kblk][3], acc3, 0, 0, 0);
      __builtin_amdgcn_s_setprio(0);
    }
  }

  // ---- 2-round pairwise LSE merge: (0<-2, 1<-3) then (0<-1) ----
  auto dump = [&](int s, const f32x16& a, int K) {
#pragma unroll
    for (int r = 0; r < 16; ++r)
      shm_acc[s][l][(K * 16 + r + l) & 63] = a[r];
  };
  auto merge_from = [&](int s) {
    float m2 = shm_m[s][l], l2 = shm_l[s][l];
    float M = fmaxf(m_run, m2);
    float aA = __expf(m_run - M), aB = __expf(m2 - M);
    l_run = aA * l_run + aB * l2;
    m_run = M;
    float aAr[16], aBr[16];
#pragma unroll
    for (int r = 0; r < 16; ++r) {
      int rowl = (r & 3) + 8 * (r >> 2) + 4 * g5;
      aAr[r] = __shfl(aA, rowl);
      aBr[r] = __shfl(aB, rowl);
    }
#pragma unroll
    for (int r = 0; r < 16; ++r) {
      acc0[r] = aAr[r] * acc0[r] + aBr[r] * shm_acc[s][l][(0 * 16 + r + l) & 63];
      acc1[r] = aAr[r] * acc1[r] + aBr[r] * shm_acc[s][l][(1 * 16 + r + l) & 63];
      acc2[r] = aAr[r] * acc2[r] + aBr[r] * shm_acc[s][l][(2 * 16 + r + l) & 63];
      acc3[r] = aAr[r] * acc3[r] + aBr[r] * shm_acc[s][l][(3 * 16 + r + l) & 63];
    }
  };

  if (w >= 2) {
    int s = w - 2;
    shm_m[s][l] = m_run; shm_l[s][l] = l_run;
    dump(s, acc0, 0); dump(s, acc1, 1); dump(s, acc2, 2); dump(s, acc3, 3);
  }
  __syncthreads();
  if (w < 2) merge_from(w);
  __syncthreads();
  if (w == 1) {
    shm_m[0][l] = m_run; shm_l[0][l] = l_run;
    dump(0, acc0, 0); dump(0, acc1, 1); dump(0, acc2, 2); dump(0, acc3, 3);
  }
  __syncthreads();
  if (w == 0) {
    merge_from(0);
    float inv = 1.f / l_run;
    int qr = qblk * 32;
#pragma unroll
    for (int r = 0; r < 16; ++r) {
      int rowl = (r & 3) + 8 * (r >> 2) + 4 * g5;
      float invr = __shfl(inv, rowl);
      float* op = O + (size_t)(qr + rowl) * 128 + l31;
      op[0]  = acc0[r] * invr;
      op[32] = acc1[r] * invr;
      op[64] = acc2[r] * invr;
      op[96] = acc3[r] * invr;
    }
  }
}

// ---------------------------------------------------------------------------
extern "C" void kernel_launch(void* const* d_in, const int* in_sizes, int n_in,
                              void* d_out, int out_size, void* d_ws, size_t ws_size,
                              hipStream_t stream) {
  const float* A  = (const float*)d_in[0];
  const float* Bm = (const float*)d_in[1];
  const float* W1 = (const float*)d_in[2];
  const float* b1 = (const float*)d_in[3];
  const float* W2 = (const float*)d_in[4];
  const float* b2 = (const float*)d_in[5];
  float* out = (float*)d_out;

  // ws (ushort units): hA,hB,fA,fB [16384][256]; At,Bt [4][128][4096]; Wt1,Wt2
  ushort* ws = (ushort*)d_ws;
  ushort* hA  = ws;
  ushort* hB  = hA + 4194304;
  ushort* fA  = hB + 4194304;
  ushort* fB  = fA + 4194304;
  ushort* At  = fB + 4194304;
  ushort* Bt  = At + 2097152;
  ushort* Wt1 = Bt + 2097152;
  ushort* Wt2 = Wt1 + 32768;     // total ~42.2 MB

  prep_transpose<<<dim3(64, 2, 8), 256, 0, stream>>>(A, Bm, At, Bt);
  prep_w<<<256, 256, 0, stream>>>(W1, W2, Wt1, Wt2);
  mlp2<128, true ><<<dim3(256, 2), 256, 0, stream>>>(A, Bm, Wt1, b1, hA, hB);
  mlp2<256, false><<<dim3(256, 2), 256, 0, stream>>>(hA, hB, Wt2, b2, fA, fB);
  flash6<<<dim3(8, 128), 256, 0, stream>>>(fA, fB, At, Bt, out);
}

// Round 8
// 260.634 us; speedup vs baseline: 4.9111x; 4.9111x over previous
//
#include <hip/hip_runtime.h>

typedef __attribute__((ext_vector_type(8))) short bf16x8;
typedef __attribute__((ext_vector_type(4))) float f32x4;
typedef __attribute__((ext_vector_type(16))) float f32x16;

__device__ __forceinline__ ushort f2bf(float x) {
  union { float f; unsigned u; } c; c.f = x;
  unsigned u = c.u;
  u += 0x7fffu + ((u >> 16) & 1u);
  return (ushort)(u >> 16);
}

__device__ __forceinline__ unsigned cvt_pk_bf16(float lo, float hi) {
  unsigned r;
  asm("v_cvt_pk_bf16_f32 %0, %1, %2" : "=v"(r) : "v"(lo), "v"(hi));
  return r;
}

__device__ __forceinline__ void gl_lds16(const void* g, void* s) {
  __builtin_amdgcn_global_load_lds(
      (const __attribute__((address_space(1))) unsigned*)g,
      (__attribute__((address_space(3))) unsigned*)s, 16, 0, 0);
}

// ---------------------------------------------------------------------------
// Transpose A,B [4][4096][128] f32 -> At,Bt [4][128][4096] bf16 (V^T operands)
// ---------------------------------------------------------------------------
__global__ __launch_bounds__(256) void prep_transpose(
    const float* __restrict__ A, const float* __restrict__ Bm,
    ushort* __restrict__ At, ushort* __restrict__ Bt)
{
  int tensor = blockIdx.z & 1, b = blockIdx.z >> 1;
  const float* in = tensor ? Bm : A;
  ushort* out = tensor ? Bt : At;
  int m0 = blockIdx.x * 64, d0 = blockIdx.y * 64;
  __shared__ ushort tile[64][72];
  int tid = threadIdx.x;
#pragma unroll
  for (int it = 0; it < 4; ++it) {
    int lin = it * 256 + tid;
    int r = lin >> 4, c4 = (lin & 15) * 4;
    const float* p = in + ((size_t)b * 4096 + m0 + r) * 128 + d0 + c4;
    float4 v = *(const float4*)p;
    tile[r][c4 + 0] = f2bf(v.x); tile[r][c4 + 1] = f2bf(v.y);
    tile[r][c4 + 2] = f2bf(v.z); tile[r][c4 + 3] = f2bf(v.w);
  }
  __syncthreads();
#pragma unroll
  for (int it = 0; it < 2; ++it) {
    int lin = it * 256 + tid;
    int dr = lin >> 3, cm = (lin & 7) * 8;
    bf16x8 v;
#pragma unroll
    for (int j = 0; j < 8; ++j) v[j] = (short)tile[cm + j][dr];
    *(bf16x8*)(out + ((size_t)b * 128 + d0 + dr) * 4096 + m0 + cm) = v;
  }
}

// ---------------------------------------------------------------------------
// W1[128][256] -> Wt1[256][128] bf16 ; W2[256][256] -> Wt2[256][256] bf16
// ---------------------------------------------------------------------------
__global__ __launch_bounds__(256) void prep_w(
    const float* __restrict__ W1, const float* __restrict__ W2,
    ushort* __restrict__ Wt1, ushort* __restrict__ Wt2)
{
  int idx = blockIdx.x * 256 + threadIdx.x;   // 0..65535
  if (idx < 32768) {
    int k = idx >> 8, n = idx & 255;
    Wt1[n * 128 + k] = f2bf(W1[idx]);
  }
  {
    int k = idx >> 8, n = idx & 255;
    Wt2[n * 256 + k] = f2bf(W2[idx]);
  }
}

// ---------------------------------------------------------------------------
// out = relu(X @ W + bias) bf16, N=256. Wt bf16 [256][KD] from global (L2).
// ---------------------------------------------------------------------------
template<int KD, bool F32IN>
__global__ __launch_bounds__(256) void mlp2(
    const void* __restrict__ X0, const void* __restrict__ X1,
    const ushort* __restrict__ Wt, const float* __restrict__ bias,
    ushort* __restrict__ out0, ushort* __restrict__ out1)
{
  const void* X = blockIdx.y ? X1 : X0;
  ushort* out = blockIdx.y ? out1 : out0;
  int l = threadIdx.x & 63, w = threadIdx.x >> 6;
  int rowbase = blockIdx.x * 64 + w * 16;
  constexpr int NK = KD / 32;
  bf16x8 xf[NK];
  {
    int r = rowbase + (l & 15);
    int koff = (l >> 4) * 8;
    if (F32IN) {
      const float* Xp = (const float*)X + (size_t)r * KD + koff;
#pragma unroll
      for (int kc = 0; kc < NK; ++kc) {
        float4 a = *(const float4*)(Xp + kc * 32);
        float4 c = *(const float4*)(Xp + kc * 32 + 4);
        bf16x8 v;
        v[0] = (short)f2bf(a.x); v[1] = (short)f2bf(a.y);
        v[2] = (short)f2bf(a.z); v[3] = (short)f2bf(a.w);
        v[4] = (short)f2bf(c.x); v[5] = (short)f2bf(c.y);
        v[6] = (short)f2bf(c.z); v[7] = (short)f2bf(c.w);
        xf[kc] = v;
      }
    } else {
      const ushort* Xp = (const ushort*)X + (size_t)r * KD + koff;
#pragma unroll
      for (int kc = 0; kc < NK; ++kc) xf[kc] = *(const bf16x8*)(Xp + kc * 32);
    }
  }
  f32x4 acc[16];
#pragma unroll
  for (int i = 0; i < 16; ++i) acc[i] = (f32x4){0.f, 0.f, 0.f, 0.f};
#pragma unroll
  for (int kc = 0; kc < NK; ++kc) {
#pragma unroll
    for (int nf = 0; nf < 16; ++nf) {
      bf16x8 bfv = *(const bf16x8*)&Wt[(size_t)(nf * 16 + (l & 15)) * KD + kc * 32 + (l >> 4) * 8];
      acc[nf] = __builtin_amdgcn_mfma_f32_16x16x32_bf16(xf[kc], bfv, acc[nf], 0, 0, 0);
    }
  }
#pragma unroll
  for (int nf = 0; nf < 16; ++nf) {
    int col = nf * 16 + (l & 15);
    float bv = bias[col];
#pragma unroll
    for (int i = 0; i < 4; ++i) {
      float v = acc[nf][i] + bv;
      v = fmaxf(v, 0.f);
      out[(size_t)(rowbase + (l >> 4) * 4 + i) * 256 + col] = f2bf(v);
    }
  }
}

// ---------------------------------------------------------------------------
// Flash pass (r3 structure + proven micro-fixes). Split-K across waves:
// block = 4 waves = (qw, kw); 64 q-rows; wave = 32 q-rows x 32 keys per
// 64-key LDS tile (dbuf, global_load_lds, FULL 5-bit XOR swizzle -> 0 bank
// conflicts, r4/r6-measured). V loads issued BEFORE stage(t+1) so the
// compiler's V-wait at PV does not retire the prefetch early. Plain
// __syncthreads (no pins: m141). Grid (8,64) = 512 blocks, 2 blocks/CU.
// End merge of (m,l,acc) between kw partners via LDS.
// ---------------------------------------------------------------------------
__global__ __launch_bounds__(256, 2) void flash8(
    const ushort* __restrict__ fA, const ushort* __restrict__ fB,
    const ushort* __restrict__ At, const ushort* __restrict__ Bt,
    float* __restrict__ out)
{
  int bp = blockIdx.x;
  int pass = bp >> 2, b = bp & 3;
  int qbase = blockIdx.y * 64;
  const ushort* fQ = pass ? fB : fA;
  const ushort* fK = pass ? fA : fB;
  const ushort* Vg = pass ? At : Bt;
  float* O = out + (size_t)pass * (4u * 4096 * 128) + (size_t)b * 4096 * 128;

  __shared__ ushort Kl[2][64 * 256];   // 64 KB (reused for final merge)

  int tid = threadIdx.x;
  int l = tid & 63, w = tid >> 6;
  int l31 = l & 31, g5 = l >> 5;
  int qw = w & 1, kw = w >> 1;

  const size_t fkbase = (size_t)b * 4096 * 256;
  const size_t vgbase = (size_t)b * 128 * 4096;

  // LDS[row][j] = G[row][j ^ (row&31)]  (full 5-bit swizzle; measured 0 cf)
  auto stage_k = [&](int t_, int buf_) {
    const ushort* kp = fK + fkbase + (size_t)t_ * 16384;
    ushort* lb = &Kl[buf_][0] + w * 4096;
#pragma unroll
    for (int s = 0; s < 8; ++s) {
      int row = w * 16 + s * 2 + g5;
      int gs = l31 ^ (row & 31);
      gl_lds16(kp + (size_t)row * 256 + gs * 8, lb + s * 512);
    }
  };

  // Q regs: B-frag (col = l31 -> qrow, h = kc*16 + g5*8 + j)
  bf16x8 q[16];
  {
    const ushort* qp = fQ + fkbase + (size_t)(qbase + qw * 32 + l31) * 256 + g5 * 8;
#pragma unroll
    for (int kc = 0; kc < 16; ++kc) q[kc] = *(const bf16x8*)(qp + kc * 16);
  }

  f32x16 acc_o0 = {}, acc_o1 = {}, acc_o2 = {}, acc_o3 = {};
  float m_run = -INFINITY, l_run = 0.f;

  stage_k(0, 0);

  for (int t = 0; t < 64; ++t) {
    int cur = t & 1;
    __syncthreads();               // staged K[t] drained; prev reads done

    // V^T loads FIRST (L2): younger stage ops then ride past the PV V-wait.
    bf16x8 vv[2][4];
#pragma unroll
    for (int dblk = 0; dblk < 4; ++dblk) {
      const ushort* vp = Vg + vgbase + (size_t)(dblk * 32 + l31) * 4096
                         + t * 64 + kw * 32 + g5 * 8;
      vv[0][dblk] = *(const bf16x8*)(vp);
      vv[1][dblk] = *(const bf16x8*)(vp + 16);
    }

    if (t < 63) stage_k(t + 1, cur ^ 1);

    // QK^T swapped: S^T[key][qrow] = mfma(A=K, B=Q). 2 indep chains.
    const ushort* kbuf = &Kl[cur][0];
    int krow = kw * 32 + l31;                   // krow & 31 == l31
    f32x16 s0 = {}, s1 = {};
    __builtin_amdgcn_s_setprio(1);
#pragma unroll
    for (int kc = 0; kc < 8; ++kc) {
      bf16x8 a0 = *(const bf16x8*)&kbuf[krow * 256 + (((4 * kc + g5)     ^ l31) * 8)];
      bf16x8 a1 = *(const bf16x8*)&kbuf[krow * 256 + (((4 * kc + 2 + g5) ^ l31) * 8)];
      s0 = __builtin_amdgcn_mfma_f32_32x32x16_bf16(a0, q[2 * kc],     s0, 0, 0, 0);
      s1 = __builtin_amdgcn_mfma_f32_32x32x16_bf16(a1, q[2 * kc + 1], s1, 0, 0, 0);
    }
    __builtin_amdgcn_s_setprio(0);

    // lane: qrow = l31; key-local(r,g5) = (r&3) + 8*(r>>2) + 4*g5
    float sv[16];
#pragma unroll
    for (int r = 0; r < 16; ++r) sv[r] = s0[r] + s1[r];

    // tree max (dep depth 4)
    float mx[16];
#pragma unroll
    for (int r = 0; r < 16; ++r) mx[r] = sv[r];
#pragma unroll
    for (int off = 8; off >= 1; off >>= 1)
#pragma unroll
      for (int r = 0; r < off; ++r) mx[r] = fmaxf(mx[r], mx[r + off]);
    float pmax = fmaxf(mx[0], __shfl_xor(mx[0], 32));

    if (!__all(pmax <= m_run + 8.f)) {       // rare: t=0 / overflow risk only
      float mnew = fmaxf(m_run, pmax);
      float sc = __expf(m_run - mnew);
      l_run *= sc;
#pragma unroll
      for (int r = 0; r < 16; ++r) {
        float scr = __shfl(sc, (r & 3) + 8 * (r >> 2) + 4 * g5);
        acc_o0[r] *= scr; acc_o1[r] *= scr; acc_o2[r] *= scr; acc_o3[r] *= scr;
      }
      m_run = mnew;
    }

    float p[16];
#pragma unroll
    for (int r = 0; r < 16; ++r) p[r] = __expf(sv[r] - m_run);
    float ps[16];
#pragma unroll
    for (int r = 0; r < 16; ++r) ps[r] = p[r];
#pragma unroll
    for (int off = 8; off >= 1; off >>= 1)
#pragma unroll
      for (int r = 0; r < off; ++r) ps[r] += ps[r + off];
    l_run += ps[0] + __shfl_xor(ps[0], 32);

    // pack P pairs: pk[r2][h] covers key-locals 4*(2*r2 + g5) + {0..3}
    unsigned pk[4][2];
#pragma unroll
    for (int r2 = 0; r2 < 4; ++r2) {
      pk[r2][0] = cvt_pk_bf16(p[4 * r2 + 0], p[4 * r2 + 1]);
      pk[r2][1] = cvt_pk_bf16(p[4 * r2 + 2], p[4 * r2 + 3]);
    }

    // exchange halves -> PV A-frags; PV MFMAs
#pragma unroll
    for (int kblk = 0; kblk < 2; ++kblk) {
      int r2a = 2 * kblk, r2b = r2a + 1;
      unsigned la0 = pk[r2a][0], la1 = pk[r2a][1];
      unsigned lb0 = pk[r2b][0], lb1 = pk[r2b][1];
      unsigned s0w = g5 ? la0 : lb0, s1w = g5 ? la1 : lb1;
      unsigned rc0 = (unsigned)__shfl_xor((int)s0w, 32);
      unsigned rc1 = (unsigned)__shfl_xor((int)s1w, 32);
      union { unsigned u[4]; bf16x8 v; } pf;
      pf.u[0] = g5 ? rc0 : la0;  pf.u[1] = g5 ? rc1 : la1;
      pf.u[2] = g5 ? lb0 : rc0;  pf.u[3] = g5 ? lb1 : rc1;
      __builtin_amdgcn_s_setprio(1);
      acc_o0 = __builtin_amdgcn_mfma_f32_32x32x16_bf16(pf.v, vv[kblk][0], acc_o0, 0, 0, 0);
      acc_o1 = __builtin_amdgcn_mfma_f32_32x32x16_bf16(pf.v, vv[kblk][1], acc_o1, 0, 0, 0);
      acc_o2 = __builtin_amdgcn_mfma_f32_32x32x16_bf16(pf.v, vv[kblk][2], acc_o2, 0, 0, 0);
      acc_o3 = __builtin_amdgcn_mfma_f32_32x32x16_bf16(pf.v, vv[kblk][3], acc_o3, 0, 0, 0);
      __builtin_amdgcn_s_setprio(0);
    }
  }

  // ---- merge kw partners through LDS, then store ----
  __syncthreads();                 // all K reads done; Kl reusable
  float* shm = (float*)&Kl[0][0];
  shm[w * 128 + l] = m_run;
  shm[w * 128 + 64 + l] = l_run;
  {
    float* sa = shm + 512 + w * 2048;
    const f32x16& send0 = kw ? acc_o0 : acc_o2;
    const f32x16& send1 = kw ? acc_o1 : acc_o3;
#pragma unroll
    for (int r = 0; r < 16; ++r) {
      sa[r * 64 + l] = send0[r];
      sa[1024 + r * 64 + l] = send1[r];
    }
  }
  __syncthreads();
  {
    int pw = w ^ 2;
    float m1 = shm[pw * 128 + l];
    float l1 = shm[pw * 128 + 64 + l];
    float M = fmaxf(m_run, m1);
    float a0 = __expf(m_run - M), a1 = __expf(m1 - M);
    float inv = 1.f / (l_run * a0 + l1 * a1);
    const float* sp = shm + 512 + pw * 2048;
    const f32x16& keep0 = kw ? acc_o2 : acc_o0;
    const f32x16& keep1 = kw ? acc_o3 : acc_o1;
    int dbase = kw ? 64 : 0;
    int qr = qbase + qw * 32;
#pragma unroll
    for (int r = 0; r < 16; ++r) {
      int rowl = (r & 3) + 8 * (r >> 2) + 4 * g5;
      float invr = __shfl(inv, rowl);
      float a0r = __shfl(a0, rowl);
      float a1r = __shfl(a1, rowl);
      float* op = O + (size_t)(qr + rowl) * 128 + dbase + l31;
      op[0]  = (keep0[r] * a0r + sp[r * 64 + l] * a1r) * invr;
      op[32] = (keep1[r] * a0r + sp[1024 + r * 64 + l] * a1r) * invr;
    }
  }
}

// ---------------------------------------------------------------------------
extern "C" void kernel_launch(void* const* d_in, const int* in_sizes, int n_in,
                              void* d_out, int out_size, void* d_ws, size_t ws_size,
                              hipStream_t stream) {
  const float* A  = (const float*)d_in[0];
  const float* Bm = (const float*)d_in[1];
  const float* W1 = (const float*)d_in[2];
  const float* b1 = (const float*)d_in[3];
  const float* W2 = (const float*)d_in[4];
  const float* b2 = (const float*)d_in[5];
  float* out = (float*)d_out;

  // ws (ushort units): hA,hB,fA,fB [16384][256]; At,Bt [4][128][4096]; Wt1,Wt2
  ushort* ws = (ushort*)d_ws;
  ushort* hA  = ws;
  ushort* hB  = hA + 4194304;
  ushort* fA  = hB + 4194304;
  ushort* fB  = fA + 4194304;
  ushort* At  = fB + 4194304;
  ushort* Bt  = At + 2097152;
  ushort* Wt1 = Bt + 2097152;
  ushort* Wt2 = Wt1 + 32768;     // total ~42.2 MB

  prep_transpose<<<dim3(64, 2, 8), 256, 0, stream>>>(A, Bm, At, Bt);
  prep_w<<<256, 256, 0, stream>>>(W1, W2, Wt1, Wt2);
  mlp2<128, true ><<<dim3(256, 2), 256, 0, stream>>>(A, Bm, Wt1, b1, hA, hB);
  mlp2<256, false><<<dim3(256, 2), 256, 0, stream>>>(hA, hB, Wt2, b2, fA, fB);
  flash8<<<dim3(8, 64), 256, 0, stream>>>(fA, fB, At, Bt, out);
}

// Round 9
// 243.890 us; speedup vs baseline: 5.2483x; 1.0687x over previous
//
#include <hip/hip_runtime.h>

typedef __attribute__((ext_vector_type(8))) short bf16x8;
typedef __attribute__((ext_vector_type(4))) float f32x4;
typedef __attribute__((ext_vector_type(16))) float f32x16;

__device__ __forceinline__ ushort f2bf(float x) {
  union { float f; unsigned u; } c; c.f = x;
  unsigned u = c.u;
  u += 0x7fffu + ((u >> 16) & 1u);
  return (ushort)(u >> 16);
}

__device__ __forceinline__ unsigned cvt_pk_bf16(float lo, float hi) {
  unsigned r;
  asm("v_cvt_pk_bf16_f32 %0, %1, %2" : "=v"(r) : "v"(lo), "v"(hi));
  return r;
}

__device__ __forceinline__ void gl_lds16(const void* g, void* s) {
  __builtin_amdgcn_global_load_lds(
      (const __attribute__((address_space(1))) unsigned*)g,
      (__attribute__((address_space(3))) unsigned*)s, 16, 0, 0);
}

// ---------------------------------------------------------------------------
// Transpose A,B [4][4096][128] f32 -> At,Bt [4][128][4096] bf16 (V^T operands)
// ---------------------------------------------------------------------------
__global__ __launch_bounds__(256) void prep_transpose(
    const float* __restrict__ A, const float* __restrict__ Bm,
    ushort* __restrict__ At, ushort* __restrict__ Bt)
{
  int tensor = blockIdx.z & 1, b = blockIdx.z >> 1;
  const float* in = tensor ? Bm : A;
  ushort* out = tensor ? Bt : At;
  int m0 = blockIdx.x * 64, d0 = blockIdx.y * 64;
  __shared__ ushort tile[64][72];
  int tid = threadIdx.x;
#pragma unroll
  for (int it = 0; it < 4; ++it) {
    int lin = it * 256 + tid;
    int r = lin >> 4, c4 = (lin & 15) * 4;
    const float* p = in + ((size_t)b * 4096 + m0 + r) * 128 + d0 + c4;
    float4 v = *(const float4*)p;
    tile[r][c4 + 0] = f2bf(v.x); tile[r][c4 + 1] = f2bf(v.y);
    tile[r][c4 + 2] = f2bf(v.z); tile[r][c4 + 3] = f2bf(v.w);
  }
  __syncthreads();
#pragma unroll
  for (int it = 0; it < 2; ++it) {
    int lin = it * 256 + tid;
    int dr = lin >> 3, cm = (lin & 7) * 8;
    bf16x8 v;
#pragma unroll
    for (int j = 0; j < 8; ++j) v[j] = (short)tile[cm + j][dr];
    *(bf16x8*)(out + ((size_t)b * 128 + d0 + dr) * 4096 + m0 + cm) = v;
  }
}

// ---------------------------------------------------------------------------
// W1[128][256] -> Wt1[256][128] bf16 ; W2[256][256] -> Wt2[256][256] bf16
// ---------------------------------------------------------------------------
__global__ __launch_bounds__(256) void prep_w(
    const float* __restrict__ W1, const float* __restrict__ W2,
    ushort* __restrict__ Wt1, ushort* __restrict__ Wt2)
{
  int idx = blockIdx.x * 256 + threadIdx.x;   // 0..65535
  if (idx < 32768) {
    int k = idx >> 8, n = idx & 255;
    Wt1[n * 128 + k] = f2bf(W1[idx]);
  }
  {
    int k = idx >> 8, n = idx & 255;
    Wt2[n * 256 + k] = f2bf(W2[idx]);
  }
}

// ---------------------------------------------------------------------------
// out = relu(X @ W + bias) bf16, N=256. Wt bf16 [256][KD] from global (L2).
// ---------------------------------------------------------------------------
template<int KD, bool F32IN>
__global__ __launch_bounds__(256) void mlp2(
    const void* __restrict__ X0, const void* __restrict__ X1,
    const ushort* __restrict__ Wt, const float* __restrict__ bias,
    ushort* __restrict__ out0, ushort* __restrict__ out1)
{
  const void* X = blockIdx.y ? X1 : X0;
  ushort* out = blockIdx.y ? out1 : out0;
  int l = threadIdx.x & 63, w = threadIdx.x >> 6;
  int rowbase = blockIdx.x * 64 + w * 16;
  constexpr int NK = KD / 32;
  bf16x8 xf[NK];
  {
    int r = rowbase + (l & 15);
    int koff = (l >> 4) * 8;
    if (F32IN) {
      const float* Xp = (const float*)X + (size_t)r * KD + koff;
#pragma unroll
      for (int kc = 0; kc < NK; ++kc) {
        float4 a = *(const float4*)(Xp + kc * 32);
        float4 c = *(const float4*)(Xp + kc * 32 + 4);
        bf16x8 v;
        v[0] = (short)f2bf(a.x); v[1] = (short)f2bf(a.y);
        v[2] = (short)f2bf(a.z); v[3] = (short)f2bf(a.w);
        v[4] = (short)f2bf(c.x); v[5] = (short)f2bf(c.y);
        v[6] = (short)f2bf(c.z); v[7] = (short)f2bf(c.w);
        xf[kc] = v;
      }
    } else {
      const ushort* Xp = (const ushort*)X + (size_t)r * KD + koff;
#pragma unroll
      for (int kc = 0; kc < NK; ++kc) xf[kc] = *(const bf16x8*)(Xp + kc * 32);
    }
  }
  f32x4 acc[16];
#pragma unroll
  for (int i = 0; i < 16; ++i) acc[i] = (f32x4){0.f, 0.f, 0.f, 0.f};
#pragma unroll
  for (int kc = 0; kc < NK; ++kc) {
#pragma unroll
    for (int nf = 0; nf < 16; ++nf) {
      bf16x8 bfv = *(const bf16x8*)&Wt[(size_t)(nf * 16 + (l & 15)) * KD + kc * 32 + (l >> 4) * 8];
      acc[nf] = __builtin_amdgcn_mfma_f32_16x16x32_bf16(xf[kc], bfv, acc[nf], 0, 0, 0);
    }
  }
#pragma unroll
  for (int nf = 0; nf < 16; ++nf) {
    int col = nf * 16 + (l & 15);
    float bv = bias[col];
#pragma unroll
    for (int i = 0; i < 4; ++i) {
      float v = acc[nf][i] + bv;
      v = fmaxf(v, 0.f);
      out[(size_t)(rowbase + (l >> 4) * 4 + i) * 256 + col] = f2bf(v);
    }
  }
}

// ---------------------------------------------------------------------------
// Flash pass = r3 structure (proven 190us) + 5-bit XOR swizzle (0 conflicts,
// measured r4/r6/r8) + speculative exp (pmax tree off the critical path) +
// pack/PV interleave + NO setprio (m190: hurts lockstep blocks).
// Block = 4 waves = (qw, kw); 64 q-rows; wave = 32 q-rows x 32 keys of each
// 64-key LDS K tile (dbuf, global_load_lds). Grid (8,64), 2 blocks/CU.
// End merge of (m,l,acc) between kw partners via LDS.
// ---------------------------------------------------------------------------
__global__ __launch_bounds__(256, 2) void flash9(
    const ushort* __restrict__ fA, const ushort* __restrict__ fB,
    const ushort* __restrict__ At, const ushort* __restrict__ Bt,
    float* __restrict__ out)
{
  int bp = blockIdx.x;
  int pass = bp >> 2, b = bp & 3;
  int qbase = blockIdx.y * 64;
  const ushort* fQ = pass ? fB : fA;
  const ushort* fK = pass ? fA : fB;
  const ushort* Vg = pass ? At : Bt;
  float* O = out + (size_t)pass * (4u * 4096 * 128) + (size_t)b * 4096 * 128;

  __shared__ ushort Kl[2][64 * 256];   // 64 KB (reused for final merge)

  int tid = threadIdx.x;
  int l = tid & 63, w = tid >> 6;
  int l31 = l & 31, g5 = l >> 5;
  int qw = w & 1, kw = w >> 1;

  const size_t fkbase = (size_t)b * 4096 * 256;
  const size_t vgbase = (size_t)b * 128 * 4096;

  // LDS[row][g] = G[row][g ^ (row&31)]  (full 5-bit swizzle; measured 0 cf)
  auto stage_k = [&](int t_, int buf_) {
    const ushort* kp = fK + fkbase + (size_t)t_ * 16384;
    ushort* lb = &Kl[buf_][0] + w * 4096;
#pragma unroll
    for (int s = 0; s < 8; ++s) {
      int row = w * 16 + s * 2 + g5;
      int gs = l31 ^ (row & 31);
      gl_lds16(kp + (size_t)row * 256 + gs * 8, lb + s * 512);
    }
  };

  // Q regs: B-frag (col = l31 -> qrow, h = kc*16 + g5*8 + j)
  bf16x8 q[16];
  {
    const ushort* qp = fQ + fkbase + (size_t)(qbase + qw * 32 + l31) * 256 + g5 * 8;
#pragma unroll
    for (int kc = 0; kc < 16; ++kc) q[kc] = *(const bf16x8*)(qp + kc * 16);
  }

  f32x16 acc_o0 = {}, acc_o1 = {}, acc_o2 = {}, acc_o3 = {};
  float m_run = 0.f, l_run = 0.f;   // m=0 init: scores O(5), exp can't overflow

  stage_k(0, 0);

  for (int t = 0; t < 64; ++t) {
    int cur = t & 1;
    __syncthreads();               // staged K[t] drained; prev reads done
    if (t < 63) stage_k(t + 1, cur ^ 1);

    // V^T loads (L2): B-frag col = l31 -> d-local, k = key-local
    bf16x8 vv[2][4];
#pragma unroll
    for (int dblk = 0; dblk < 4; ++dblk) {
      const ushort* vp = Vg + vgbase + (size_t)(dblk * 32 + l31) * 4096
                         + t * 64 + kw * 32 + g5 * 8;
      vv[0][dblk] = *(const bf16x8*)(vp);
      vv[1][dblk] = *(const bf16x8*)(vp + 16);
    }

    // QK^T swapped: S^T[key][qrow] = mfma(A=K, B=Q). 2 indep chains.
    const ushort* kbuf = &Kl[cur][0];
    int krow = kw * 32 + l31;                   // krow & 31 == l31
    f32x16 s0 = {}, s1 = {};
#pragma unroll
    for (int kc = 0; kc < 8; ++kc) {
      bf16x8 a0 = *(const bf16x8*)&kbuf[krow * 256 + (((4 * kc + g5)     ^ l31) * 8)];
      bf16x8 a1 = *(const bf16x8*)&kbuf[krow * 256 + (((4 * kc + 2 + g5) ^ l31) * 8)];
      s0 = __builtin_amdgcn_mfma_f32_32x32x16_bf16(a0, q[2 * kc],     s0, 0, 0, 0);
      s1 = __builtin_amdgcn_mfma_f32_32x32x16_bf16(a1, q[2 * kc + 1], s1, 0, 0, 0);
    }

    // lane: qrow = l31; key-local(r,g5) = (r&3) + 8*(r>>2) + 4*g5
    float sv[16];
#pragma unroll
    for (int r = 0; r < 16; ++r) sv[r] = s0[r] + s1[r];

    // speculative exp with current m_run (valid unless defer-check fails),
    // overlapping the pmax tree (both depend only on sv).
    float p[16];
#pragma unroll
    for (int r = 0; r < 16; ++r) p[r] = __expf(sv[r] - m_run);

    float mx[16];
#pragma unroll
    for (int r = 0; r < 16; ++r) mx[r] = sv[r];
#pragma unroll
    for (int off = 8; off >= 1; off >>= 1)
#pragma unroll
      for (int r = 0; r < off; ++r) mx[r] = fmaxf(mx[r], mx[r + off]);
    float pmax = fmaxf(mx[0], __shfl_xor(mx[0], 32));

    if (!__all(pmax <= m_run + 8.f)) {   // rare: large-score rows only
      float mnew = fmaxf(m_run, pmax);
      float sc = __expf(m_run - mnew);
      l_run *= sc;
#pragma unroll
      for (int r = 0; r < 16; ++r) {
        float scr = __shfl(sc, (r & 3) + 8 * (r >> 2) + 4 * g5);
        acc_o0[r] *= scr; acc_o1[r] *= scr; acc_o2[r] *= scr; acc_o3[r] *= scr;
      }
#pragma unroll
      for (int r = 0; r < 16; ++r) p[r] = __expf(sv[r] - mnew);
      m_run = mnew;
    }

    // kblk0: pack p[0..7], exchange halves, PV (VALU of kblk1 overlaps these MFMAs)
    {
      unsigned la0 = cvt_pk_bf16(p[0], p[1]), la1 = cvt_pk_bf16(p[2], p[3]);
      unsigned lb0 = cvt_pk_bf16(p[4], p[5]), lb1 = cvt_pk_bf16(p[6], p[7]);
      unsigned s0w = g5 ? la0 : lb0, s1w = g5 ? la1 : lb1;
      unsigned rc0 = (unsigned)__shfl_xor((int)s0w, 32);
      unsigned rc1 = (unsigned)__shfl_xor((int)s1w, 32);
      union { unsigned u[4]; bf16x8 v; } pf;
      pf.u[0] = g5 ? rc0 : la0;  pf.u[1] = g5 ? rc1 : la1;
      pf.u[2] = g5 ? lb0 : rc0;  pf.u[3] = g5 ? lb1 : rc1;
      acc_o0 = __builtin_amdgcn_mfma_f32_32x32x16_bf16(pf.v, vv[0][0], acc_o0, 0, 0, 0);
      acc_o1 = __builtin_amdgcn_mfma_f32_32x32x16_bf16(pf.v, vv[0][1], acc_o1, 0, 0, 0);
      acc_o2 = __builtin_amdgcn_mfma_f32_32x32x16_bf16(pf.v, vv[0][2], acc_o2, 0, 0, 0);
      acc_o3 = __builtin_amdgcn_mfma_f32_32x32x16_bf16(pf.v, vv[0][3], acc_o3, 0, 0, 0);
    }
    // kblk1: pack p[8..15], exchange, PV
    {
      unsigned la0 = cvt_pk_bf16(p[8],  p[9]),  la1 = cvt_pk_bf16(p[10], p[11]);
      unsigned lb0 = cvt_pk_bf16(p[12], p[13]), lb1 = cvt_pk_bf16(p[14], p[15]);
      unsigned s0w = g5 ? la0 : lb0, s1w = g5 ? la1 : lb1;
      unsigned rc0 = (unsigned)__shfl_xor((int)s0w, 32);
      unsigned rc1 = (unsigned)__shfl_xor((int)s1w, 32);
      union { unsigned u[4]; bf16x8 v; } pf;
      pf.u[0] = g5 ? rc0 : la0;  pf.u[1] = g5 ? rc1 : la1;
      pf.u[2] = g5 ? lb0 : rc0;  pf.u[3] = g5 ? lb1 : rc1;
      acc_o0 = __builtin_amdgcn_mfma_f32_32x32x16_bf16(pf.v, vv[1][0], acc_o0, 0, 0, 0);
      acc_o1 = __builtin_amdgcn_mfma_f32_32x32x16_bf16(pf.v, vv[1][1], acc_o1, 0, 0, 0);
      acc_o2 = __builtin_amdgcn_mfma_f32_32x32x16_bf16(pf.v, vv[1][2], acc_o2, 0, 0, 0);
      acc_o3 = __builtin_amdgcn_mfma_f32_32x32x16_bf16(pf.v, vv[1][3], acc_o3, 0, 0, 0);
    }

    // psum tree last: runs under the PV MFMA tail
    float ps[16];
#pragma unroll
    for (int r = 0; r < 16; ++r) ps[r] = p[r];
#pragma unroll
    for (int off = 8; off >= 1; off >>= 1)
#pragma unroll
      for (int r = 0; r < off; ++r) ps[r] += ps[r + off];
    l_run += ps[0] + __shfl_xor(ps[0], 32);
  }

  // ---- merge kw partners through LDS, then store ----
  __syncthreads();                 // all K reads done; Kl reusable
  float* shm = (float*)&Kl[0][0];
  shm[w * 128 + l] = m_run;
  shm[w * 128 + 64 + l] = l_run;
  {
    float* sa = shm + 512 + w * 2048;
    const f32x16& send0 = kw ? acc_o0 : acc_o2;
    const f32x16& send1 = kw ? acc_o1 : acc_o3;
#pragma unroll
    for (int r = 0; r < 16; ++r) {
      sa[r * 64 + l] = send0[r];
      sa[1024 + r * 64 + l] = send1[r];
    }
  }
  __syncthreads();
  {
    int pw = w ^ 2;
    float m1 = shm[pw * 128 + l];
    float l1 = shm[pw * 128 + 64 + l];
    float M = fmaxf(m_run, m1);
    float a0 = __expf(m_run - M), a1 = __expf(m1 - M);
    float inv = 1.f / (l_run * a0 + l1 * a1);
    const float* sp = shm + 512 + pw * 2048;
    const f32x16& keep0 = kw ? acc_o2 : acc_o0;
    const f32x16& keep1 = kw ? acc_o3 : acc_o1;
    int dbase = kw ? 64 : 0;
    int qr = qbase + qw * 32;
#pragma unroll
    for (int r = 0; r < 16; ++r) {
      int rowl = (r & 3) + 8 * (r >> 2) + 4 * g5;
      float invr = __shfl(inv, rowl);
      float a0r = __shfl(a0, rowl);
      float a1r = __shfl(a1, rowl);
      float* op = O + (size_t)(qr + rowl) * 128 + dbase + l31;
      op[0]  = (keep0[r] * a0r + sp[r * 64 + l] * a1r) * invr;
      op[32] = (keep1[r] * a0r + sp[1024 + r * 64 + l] * a1r) * invr;
    }
  }
}

// ---------------------------------------------------------------------------
extern "C" void kernel_launch(void* const* d_in, const int* in_sizes, int n_in,
                              void* d_out, int out_size, void* d_ws, size_t ws_size,
                              hipStream_t stream) {
  const float* A  = (const float*)d_in[0];
  const float* Bm = (const float*)d_in[1];
  const float* W1 = (const float*)d_in[2];
  const float* b1 = (const float*)d_in[3];
  const float* W2 = (const float*)d_in[4];
  const float* b2 = (const float*)d_in[5];
  float* out = (float*)d_out;

  // ws (ushort units): hA,hB,fA,fB [16384][256]; At,Bt [4][128][4096]; Wt1,Wt2
  ushort* ws = (ushort*)d_ws;
  ushort* hA  = ws;
  ushort* hB  = hA + 4194304;
  ushort* fA  = hB + 4194304;
  ushort* fB  = fA + 4194304;
  ushort* At  = fB + 4194304;
  ushort* Bt  = At + 2097152;
  ushort* Wt1 = Bt + 2097152;
  ushort* Wt2 = Wt1 + 32768;     // total ~42.2 MB

  prep_transpose<<<dim3(64, 2, 8), 256, 0, stream>>>(A, Bm, At, Bt);
  prep_w<<<256, 256, 0, stream>>>(W1, W2, Wt1, Wt2);
  mlp2<128, true ><<<dim3(256, 2), 256, 0, stream>>>(A, Bm, Wt1, b1, hA, hB);
  mlp2<256, false><<<dim3(256, 2), 256, 0, stream>>>(hA, hB, Wt2, b2, fA, fB);
  flash9<<<dim3(8, 64), 256, 0, stream>>>(fA, fB, At, Bt, out);
}

// Round 10
// 233.292 us; speedup vs baseline: 5.4867x; 1.0454x over previous
//
#include <hip/hip_runtime.h>

typedef __attribute__((ext_vector_type(8))) short bf16x8;
typedef __attribute__((ext_vector_type(4))) float f32x4;
typedef __attribute__((ext_vector_type(16))) float f32x16;

__device__ __forceinline__ ushort f2bf(float x) {
  union { float f; unsigned u; } c; c.f = x;
  unsigned u = c.u;
  u += 0x7fffu + ((u >> 16) & 1u);
  return (ushort)(u >> 16);
}

__device__ __forceinline__ unsigned cvt_pk_bf16(float lo, float hi) {
  unsigned r;
  asm("v_cvt_pk_bf16_f32 %0, %1, %2" : "=v"(r) : "v"(lo), "v"(hi));
  return r;
}

__device__ __forceinline__ void gl_lds16(const void* g, void* s) {
  __builtin_amdgcn_global_load_lds(
      (const __attribute__((address_space(1))) unsigned*)g,
      (__attribute__((address_space(3))) unsigned*)s, 16, 0, 0);
}

// ---------------------------------------------------------------------------
// W1[128][256] -> Wt1[256][128] bf16 ; W2[256][256] -> Wt2[256][256] bf16
// ---------------------------------------------------------------------------
__global__ __launch_bounds__(256) void prep_w(
    const float* __restrict__ W1, const float* __restrict__ W2,
    ushort* __restrict__ Wt1, ushort* __restrict__ Wt2)
{
  int idx = blockIdx.x * 256 + threadIdx.x;   // 0..65535
  if (idx < 32768) {
    int k = idx >> 8, n = idx & 255;
    Wt1[n * 128 + k] = f2bf(W1[idx]);
  }
  {
    int k = idx >> 8, n = idx & 255;
    Wt2[n * 256 + k] = f2bf(W2[idx]);
  }
}

// ---------------------------------------------------------------------------
// Fused prep: per 64-row block of X (A or B, selected by blockIdx.y):
//   (a) load X f32 -> bf16 MFMA A-frags (X read ONCE from HBM)
//   (b) emit transposed Xt[b][d][m] bf16 via LDS   (was a separate kernel)
//   (c) h = relu(X @ W1 + b1) via MFMA, handed through LDS (no HBM h)
//   (d) f = relu(h @ W2 + b2) -> fA/fB bf16
// 4 waves x 16 rows; Wt1/Wt2 bf16 read from L2 per wave (no staging).
// ---------------------------------------------------------------------------
__global__ __launch_bounds__(256) void fused_mlp(
    const float* __restrict__ A, const float* __restrict__ Bm,
    const ushort* __restrict__ Wt1, const float* __restrict__ b1,
    const ushort* __restrict__ Wt2, const float* __restrict__ b2,
    ushort* __restrict__ fA, ushort* __restrict__ fB,
    ushort* __restrict__ At, ushort* __restrict__ Bt)
{
  const float* X = blockIdx.y ? Bm : A;
  ushort* outF = blockIdx.y ? fB : fA;
  ushort* outT = blockIdx.y ? Bt : At;

  __shared__ ushort Xl[64][136];   // bf16 X chunk, padded (17.4 KB)
  __shared__ ushort Hl[64][264];   // bf16 h chunk, padded (33.8 KB)

  int tid = threadIdx.x;
  int l = tid & 63, w = tid >> 6;
  int rowbase = blockIdx.x * 64 + w * 16;      // global row (0..16383)

  // ---- (a) load X rows, convert, keep frags + write Xl ----
  bf16x8 xf[4];
  {
    int r = rowbase + (l & 15);
    int koff = (l >> 4) * 8;
    const float* Xp = X + (size_t)r * 128 + koff;
#pragma unroll
    for (int kc = 0; kc < 4; ++kc) {
      float4 a = *(const float4*)(Xp + kc * 32);
      float4 c = *(const float4*)(Xp + kc * 32 + 4);
      bf16x8 v;
      v[0] = (short)f2bf(a.x); v[1] = (short)f2bf(a.y);
      v[2] = (short)f2bf(a.z); v[3] = (short)f2bf(a.w);
      v[4] = (short)f2bf(c.x); v[5] = (short)f2bf(c.y);
      v[6] = (short)f2bf(c.z); v[7] = (short)f2bf(c.w);
      xf[kc] = v;
      *(bf16x8*)&Xl[w * 16 + (l & 15)][koff + kc * 32] = v;
    }
  }

  // ---- (c1) stage-1 MFMA: h = relu(X @ W1 + b1) ----
  f32x4 acc1[16];
#pragma unroll
  for (int i = 0; i < 16; ++i) acc1[i] = (f32x4){0.f, 0.f, 0.f, 0.f};
#pragma unroll
  for (int kc = 0; kc < 4; ++kc) {
#pragma unroll
    for (int nf = 0; nf < 16; ++nf) {
      bf16x8 bfv = *(const bf16x8*)&Wt1[(size_t)(nf * 16 + (l & 15)) * 128 + kc * 32 + (l >> 4) * 8];
      acc1[nf] = __builtin_amdgcn_mfma_f32_16x16x32_bf16(xf[kc], bfv, acc1[nf], 0, 0, 0);
    }
  }
  __syncthreads();                 // Xl complete (and acc1 done per-wave)

  // ---- (b) transposed output from Xl ----
  {
    int b = (blockIdx.x * 64) >> 12;           // batch
    int m0 = (blockIdx.x * 64) & 4095;         // m within batch
    int d = tid >> 1, mh = (tid & 1) * 32;
    ushort* op = outT + ((size_t)b * 128 + d) * 4096 + m0 + mh;
#pragma unroll
    for (int g = 0; g < 4; ++g) {
      bf16x8 v;
#pragma unroll
      for (int j = 0; j < 8; ++j) v[j] = (short)Xl[mh + g * 8 + j][d];
      *(bf16x8*)(op + g * 8) = v;
    }
  }

  // ---- (c2) h -> Hl (relu + bf16) ----
#pragma unroll
  for (int nf = 0; nf < 16; ++nf) {
    int col = nf * 16 + (l & 15);
    float bv = b1[col];
#pragma unroll
    for (int i = 0; i < 4; ++i) {
      float v = fmaxf(acc1[nf][i] + bv, 0.f);
      Hl[w * 16 + (l >> 4) * 4 + i][col] = f2bf(v);
    }
  }
  __syncthreads();                 // Hl complete

  // ---- (d) stage-2 MFMA: f = relu(h @ W2 + b2) ----
  bf16x8 hf[8];
  {
    int koff = (l >> 4) * 8;
#pragma unroll
    for (int kc = 0; kc < 8; ++kc)
      hf[kc] = *(const bf16x8*)&Hl[w * 16 + (l & 15)][koff + kc * 32];
  }
  f32x4 acc2[16];
#pragma unroll
  for (int i = 0; i < 16; ++i) acc2[i] = (f32x4){0.f, 0.f, 0.f, 0.f};
#pragma unroll
  for (int kc = 0; kc < 8; ++kc) {
#pragma unroll
    for (int nf = 0; nf < 16; ++nf) {
      bf16x8 bfv = *(const bf16x8*)&Wt2[(size_t)(nf * 16 + (l & 15)) * 256 + kc * 32 + (l >> 4) * 8];
      acc2[nf] = __builtin_amdgcn_mfma_f32_16x16x32_bf16(hf[kc], bfv, acc2[nf], 0, 0, 0);
    }
  }
#pragma unroll
  for (int nf = 0; nf < 16; ++nf) {
    int col = nf * 16 + (l & 15);
    float bv = b2[col];
#pragma unroll
    for (int i = 0; i < 4; ++i) {
      float v = fmaxf(acc2[nf][i] + bv, 0.f);
      outF[(size_t)(rowbase + (l >> 4) * 4 + i) * 256 + col] = f2bf(v);
    }
  }
}

// ---------------------------------------------------------------------------
// Flash pass — r3 structure VERBATIM (best measured: 189.7 us). Split-K
// across waves: block = 4 waves = (qw, kw); 64 q-rows; wave = 32 q-rows x
// 32 keys of each 64-key LDS tile (dbuf, global_load_lds, 3-bit XOR swizzle).
// Grid (8, 64) = 512 blocks -> 2 blocks/CU. End merge of (m,l,acc) between
// kw partners via LDS.
// ---------------------------------------------------------------------------
__global__ __launch_bounds__(256, 2) void flash2(
    const ushort* __restrict__ fA, const ushort* __restrict__ fB,
    const ushort* __restrict__ At, const ushort* __restrict__ Bt,
    float* __restrict__ out)
{
  int bp = blockIdx.x;
  int pass = bp >> 2, b = bp & 3;
  int qbase = blockIdx.y * 64;
  const ushort* fQ = pass ? fB : fA;
  const ushort* fK = pass ? fA : fB;
  const ushort* Vg = pass ? At : Bt;
  float* O = out + (size_t)pass * (4u * 4096 * 128) + (size_t)b * 4096 * 128;

  __shared__ ushort Kl[2][64 * 256];   // 64 KB (also reused for final merge)

  int tid = threadIdx.x;
  int l = tid & 63, w = tid >> 6;
  int l31 = l & 31, g5 = l >> 5;
  int qw = w & 1, kw = w >> 1;

  const size_t fkbase = (size_t)b * 4096 * 256;
  const size_t vgbase = (size_t)b * 128 * 4096;

  auto stage_k = [&](int t_, int buf_) {
    const ushort* kp = fK + fkbase + (size_t)t_ * 16384;
    ushort* lb = &Kl[buf_][0] + w * 4096;
#pragma unroll
    for (int s = 0; s < 8; ++s) {
      int row = w * 16 + s * 2 + g5;
      int gs = l31 ^ (row & 7);
      gl_lds16(kp + (size_t)row * 256 + gs * 8, lb + s * 512);
    }
  };

  // Q regs: B-frag (col = l31 -> qrow, k = kc*16 + g5*8 + j)
  bf16x8 q[16];
  {
    const ushort* qp = fQ + fkbase + (size_t)(qbase + qw * 32 + l31) * 256 + g5 * 8;
#pragma unroll
    for (int kc = 0; kc < 16; ++kc) q[kc] = *(const bf16x8*)(qp + kc * 16);
  }

  f32x16 acc_o0 = {}, acc_o1 = {}, acc_o2 = {}, acc_o3 = {};
  float m_run = -INFINITY, l_run = 0.f;

  stage_k(0, 0);

  for (int t = 0; t < 64; ++t) {
    int cur = t & 1;
    __syncthreads();               // staged K[t] drained; prev reads done
    if (t < 63) stage_k(t + 1, cur ^ 1);

    // V^T loads (L2): B-frag col = l31 -> d-local, k = key-local
    bf16x8 vv[2][4];
#pragma unroll
    for (int dblk = 0; dblk < 4; ++dblk) {
      const ushort* vp = Vg + vgbase + (size_t)(dblk * 32 + l31) * 4096
                         + t * 64 + kw * 32 + g5 * 8;
#pragma unroll
      for (int kblk = 0; kblk < 2; ++kblk)
        vv[kblk][dblk] = *(const bf16x8*)(vp + kblk * 16);
    }

    // QK^T swapped: S^T[key][qrow] = mfma(A=K, B=Q). 2 indep chains.
    const ushort* kbuf = &Kl[cur][0];
    int krow = kw * 32 + l31;
    int sx = l31 & 7;
    f32x16 s0 = {}, s1 = {};
#pragma unroll
    for (int kc = 0; kc < 8; ++kc) {
      bf16x8 a0 = *(const bf16x8*)&kbuf[krow * 256 + (((4 * kc + g5) ^ sx) * 8)];
      bf16x8 a1 = *(const bf16x8*)&kbuf[krow * 256 + (((4 * kc + 2 + g5) ^ sx) * 8)];
      s0 = __builtin_amdgcn_mfma_f32_32x32x16_bf16(a0, q[2 * kc],     s0, 0, 0, 0);
      s1 = __builtin_amdgcn_mfma_f32_32x32x16_bf16(a1, q[2 * kc + 1], s1, 0, 0, 0);
    }

    // lane: qrow = l31; key-local(r,g5) = (r&3) + 8*(r>>2) + 4*g5  in [0,32)
    float sv[16];
#pragma unroll
    for (int r = 0; r < 16; ++r) sv[r] = s0[r] + s1[r];

    float pmax = sv[0];
#pragma unroll
    for (int r = 1; r < 16; ++r) pmax = fmaxf(pmax, sv[r]);
    pmax = fmaxf(pmax, __shfl_xor(pmax, 32));

    if (!__all(pmax <= m_run + 8.f)) {       // rare (t=0 / overflow risk only)
      float mnew = fmaxf(m_run, pmax);
      float sc = __expf(m_run - mnew);
      l_run *= sc;
#pragma unroll
      for (int r = 0; r < 16; ++r) {
        float scr = __shfl(sc, (r & 3) + 8 * (r >> 2) + 4 * g5);
        acc_o0[r] *= scr; acc_o1[r] *= scr; acc_o2[r] *= scr; acc_o3[r] *= scr;
      }
      m_run = mnew;
    }

    float p[16], psum = 0.f;
#pragma unroll
    for (int r = 0; r < 16; ++r) {
      p[r] = __expf(sv[r] - m_run);
      psum += p[r];
    }
    l_run += psum + __shfl_xor(psum, 32);

    // pack P pairs: pk[r2][h] covers key-locals 4*(2*r2 + g5) + {0..3}
    unsigned pk[4][2];
#pragma unroll
    for (int r2 = 0; r2 < 4; ++r2) {
      pk[r2][0] = cvt_pk_bf16(p[4 * r2 + 0], p[4 * r2 + 1]);
      pk[r2][1] = cvt_pk_bf16(p[4 * r2 + 2], p[4 * r2 + 3]);
    }

    // exchange halves -> PV A-frags; PV MFMAs
#pragma unroll
    for (int kblk = 0; kblk < 2; ++kblk) {
      int r2a = 2 * kblk, r2b = r2a + 1;
      unsigned la0 = pk[r2a][0], la1 = pk[r2a][1];
      unsigned lb0 = pk[r2b][0], lb1 = pk[r2b][1];
      unsigned s0w = g5 ? la0 : lb0, s1w = g5 ? la1 : lb1;
      unsigned rc0 = (unsigned)__shfl_xor((int)s0w, 32);
      unsigned rc1 = (unsigned)__shfl_xor((int)s1w, 32);
      union { unsigned u[4]; bf16x8 v; } pf;
      pf.u[0] = g5 ? rc0 : la0;  pf.u[1] = g5 ? rc1 : la1;
      pf.u[2] = g5 ? lb0 : rc0;  pf.u[3] = g5 ? lb1 : rc1;
      acc_o0 = __builtin_amdgcn_mfma_f32_32x32x16_bf16(pf.v, vv[kblk][0], acc_o0, 0, 0, 0);
      acc_o1 = __builtin_amdgcn_mfma_f32_32x32x16_bf16(pf.v, vv[kblk][1], acc_o1, 0, 0, 0);
      acc_o2 = __builtin_amdgcn_mfma_f32_32x32x16_bf16(pf.v, vv[kblk][2], acc_o2, 0, 0, 0);
      acc_o3 = __builtin_amdgcn_mfma_f32_32x32x16_bf16(pf.v, vv[kblk][3], acc_o3, 0, 0, 0);
    }
  }

  // ---- merge kw partners through LDS, then store ----
  __syncthreads();                 // all K reads done; Kl reusable
  float* shm = (float*)&Kl[0][0];
  shm[w * 128 + l] = m_run;
  shm[w * 128 + 64 + l] = l_run;
  {
    float* sa = shm + 512 + w * 2048;
    const f32x16& send0 = kw ? acc_o0 : acc_o2;
    const f32x16& send1 = kw ? acc_o1 : acc_o3;
#pragma unroll
    for (int r = 0; r < 16; ++r) {
      sa[r * 64 + l] = send0[r];
      sa[1024 + r * 64 + l] = send1[r];
    }
  }
  __syncthreads();
  {
    int pw = w ^ 2;
    float m1 = shm[pw * 128 + l];
    float l1 = shm[pw * 128 + 64 + l];
    float M = fmaxf(m_run, m1);
    float a0 = __expf(m_run - M), a1 = __expf(m1 - M);
    float inv = 1.f / (l_run * a0 + l1 * a1);
    const float* sp = shm + 512 + pw * 2048;
    const f32x16& keep0 = kw ? acc_o2 : acc_o0;
    const f32x16& keep1 = kw ? acc_o3 : acc_o1;
    int dbase = kw ? 64 : 0;
    int qr = qbase + qw * 32;
#pragma unroll
    for (int r = 0; r < 16; ++r) {
      int rowl = (r & 3) + 8 * (r >> 2) + 4 * g5;
      float invr = __shfl(inv, rowl);
      float a0r = __shfl(a0, rowl);
      float a1r = __shfl(a1, rowl);
      float* op = O + (size_t)(qr + rowl) * 128 + dbase + l31;
      op[0]  = (keep0[r] * a0r + sp[r * 64 + l] * a1r) * invr;
      op[32] = (keep1[r] * a0r + sp[1024 + r * 64 + l] * a1r) * invr;
    }
  }
}

// ---------------------------------------------------------------------------
extern "C" void kernel_launch(void* const* d_in, const int* in_sizes, int n_in,
                              void* d_out, int out_size, void* d_ws, size_t ws_size,
                              hipStream_t stream) {
  const float* A  = (const float*)d_in[0];
  const float* Bm = (const float*)d_in[1];
  const float* W1 = (const float*)d_in[2];
  const float* b1 = (const float*)d_in[3];
  const float* W2 = (const float*)d_in[4];
  const float* b2 = (const float*)d_in[5];
  float* out = (float*)d_out;

  // ws (ushort units): fA,fB [16384][256]; At,Bt [4][128][4096]; Wt1,Wt2
  ushort* ws = (ushort*)d_ws;
  ushort* fA  = ws;
  ushort* fB  = fA + 4194304;
  ushort* At  = fB + 4194304;
  ushort* Bt  = At + 2097152;
  ushort* Wt1 = Bt + 2097152;
  ushort* Wt2 = Wt1 + 32768;     // total ~25.4 MB

  prep_w<<<256, 256, 0, stream>>>(W1, W2, Wt1, Wt2);
  fused_mlp<<<dim3(256, 2), 256, 0, stream>>>(A, Bm, Wt1, b1, Wt2, b2,
                                              fA, fB, At, Bt);
  flash2<<<dim3(8, 64), 256, 0, stream>>>(fA, fB, At, Bt, out);
}